// Round 4
// baseline (290.269 us; speedup 1.0000x reference)
//
#include <hip/hip_runtime.h>
#include <math.h>

#define NI 512
#define CC 512
#define KCL 64
#define HW49 49
#define CQ 25088   // 512*49
#define XHP 260    // xH row pitch (floats); 65 granules/row == 1 mod 8 -> staged rows hit distinct bank-granules

// Upsample matrix U[13][7], align_corners: even i -> 1 at i/2; odd i -> 0.5 at (i-1)/2,(i+1)/2
__device__ __forceinline__ float Uval(int i, int u) {
    if (i & 1) return (u == ((i - 1) >> 1) || u == ((i + 1) >> 1)) ? 0.5f : 0.0f;
    return (u == (i >> 1)) ? 1.0f : 0.0f;
}

// ---------------- K_G: build per-channel 49x49 operator (lnw folded in, lnb -> Gl) ----------------
__global__ __launch_bounds__(256) void kG(
    const float* __restrict__ c3w, const float* __restrict__ c5w, const float* __restrict__ c7w,
    const float* __restrict__ dww, const float* __restrict__ dhw, const float* __restrict__ accw,
    const float* __restrict__ lnw, const float* __restrict__ lnb,
    float* __restrict__ Gmat, float* __restrict__ Gl)
{
    const int c = blockIdx.x;
    const int t = threadIdx.x;
    __shared__ float dh[91], dw[91];
    __shared__ float Fh3[147], Fw3[147], Fh5[245], Fw5[245], Fh7[343], Fw7[343];
    __shared__ float wa3[9], wa5[25], wa7[49];
    __shared__ float Gtmp[2401];
    if (t < 91) dh[t] = dhw[t];
    if (t >= 128 && t < 219) dw[t - 128] = dww[t - 128];
    __syncthreads();
    for (int idx = t; idx < 147; idx += 256) {
        int oh = idx / 21, r = idx % 21, u = r / 3, dy = r % 3;
        float sh = 0.f, sw = 0.f;
        for (int i = 0; i < 13; i++) { int y = i - dy + 1; if (y >= 0 && y < 13) { float uu = Uval(i, u); sh += dh[oh * 13 + y] * uu; sw += dw[oh * 13 + y] * uu; } }
        Fh3[idx] = sh; Fw3[idx] = sw;
    }
    for (int idx = t; idx < 245; idx += 256) {
        int oh = idx / 35, r = idx % 35, u = r / 5, dy = r % 5;
        float sh = 0.f, sw = 0.f;
        for (int i = 0; i < 13; i++) { int y = i - dy + 2; if (y >= 0 && y < 13) { float uu = Uval(i, u); sh += dh[oh * 13 + y] * uu; sw += dw[oh * 13 + y] * uu; } }
        Fh5[idx] = sh; Fw5[idx] = sw;
    }
    for (int idx = t; idx < 343; idx += 256) {
        int oh = idx / 49, r = idx % 49, u = r / 7, dy = r % 7;
        float sh = 0.f, sw = 0.f;
        for (int i = 0; i < 13; i++) { int y = i - dy + 3; if (y >= 0 && y < 13) { float uu = Uval(i, u); sh += dh[oh * 13 + y] * uu; sw += dw[oh * 13 + y] * uu; } }
        Fh7[idx] = sh; Fw7[idx] = sw;
    }
    if (t < 9)               { float s = 0.f; for (int co = 0; co < 32; co++) s += accw[co]      * c3w[(size_t)(co * 512 + c) * 9  + t];        wa3[t] = s; }
    if (t >= 32 && t < 57)   { int q = t - 32; float s = 0.f; for (int co = 0; co < 32; co++) s += accw[32 + co] * c5w[(size_t)(co * 512 + c) * 25 + q]; wa5[q] = s; }
    if (t >= 64 && t < 113)  { int q = t - 64; float s = 0.f; for (int co = 0; co < 20; co++) s += accw[64 + co] * c7w[(size_t)(co * 512 + c) * 49 + q]; wa7[q] = s; }
    __syncthreads();
    for (int o = t; o < 2401; o += 256) {
        int q = o / 49, p = o % 49;
        int u = q / 7, v = q % 7, ow = p / 7, oh = p % 7;
        float acc = 0.f;
        #pragma unroll
        for (int dy = 0; dy < 3; dy++) { float fh = Fh3[(oh * 7 + u) * 3 + dy];
            #pragma unroll
            for (int dx = 0; dx < 3; dx++) acc += wa3[dy * 3 + dx] * fh * Fw3[(ow * 7 + v) * 3 + dx]; }
        #pragma unroll
        for (int dy = 0; dy < 5; dy++) { float fh = Fh5[(oh * 7 + u) * 5 + dy];
            #pragma unroll
            for (int dx = 0; dx < 5; dx++) acc += wa5[dy * 5 + dx] * fh * Fw5[(ow * 7 + v) * 5 + dx]; }
        #pragma unroll
        for (int dy = 0; dy < 7; dy++) { float fh = Fh7[(oh * 7 + u) * 7 + dy];
            #pragma unroll
            for (int dx = 0; dx < 7; dx++) acc += wa7[dy * 7 + dx] * fh * Fw7[(ow * 7 + v) * 7 + dx]; }
        Gtmp[o] = acc;
        Gmat[(size_t)c * 2401 + o] = acc * lnw[q];
    }
    __syncthreads();
    if (t < 49) {
        float s = 0.f;
        for (int q = 0; q < 49; q++) s += Gtmp[q * 49 + t] * lnb[q];
        Gl[c * 49 + t] = s;
    }
}

// ---------------- K_Cb: constant term of cw (incl. lnb fold via Gl) ----------------
__global__ void kCb(const float* __restrict__ c3b, const float* __restrict__ c5b, const float* __restrict__ c7b,
                    const float* __restrict__ dww, const float* __restrict__ dwb,
                    const float* __restrict__ dhw, const float* __restrict__ dhb,
                    const float* __restrict__ accw, const float* __restrict__ accb,
                    const float* __restrict__ Gl, float* __restrict__ Cb)
{
    __shared__ float A0s, A1s, Sdw[7], Sdh[7];
    int t = threadIdx.x;
    if (t == 0) {
        float a0 = 0.f, a1 = 0.f;
        for (int co = 0; co < 84; co++) {
            float aw = accw[co]; a0 += aw;
            float b = (co < 32) ? c3b[co] : ((co < 64) ? c5b[co - 32] : c7b[co - 64]);
            a1 += aw * b;
        }
        A0s = a0; A1s = a1;
    }
    if (t < 7)             { float s = 0.f; for (int xx = 0; xx < 13; xx++) s += dww[t * 13 + xx]; Sdw[t] = s; }
    if (t >= 8 && t < 15)  { int oh = t - 8; float s = 0.f; for (int y = 0; y < 13; y++) s += dhw[oh * 13 + y]; Sdh[oh] = s; }
    __syncthreads();
    if (t < 49) {
        int ow = t / 7, oh = t % 7;
        float g = 0.f;
        for (int c = 0; c < 512; c++) g += Gl[c * 49 + t];
        Cb[t] = A1s * Sdw[ow] * Sdh[oh] + A0s * (dwb[ow] * Sdh[oh] + dhb[oh]) + accb[0] + g;
    }
}

// ---------------- K_cw1: partial GEMM with inline LayerNorm  cw_partial = LN(x) x Gmat ----------------
// 256 threads/block (4 waves), 1024 blocks -> 16 waves/CU.
__global__ __launch_bounds__(256) void kCw1(const float* __restrict__ x,
    const float* __restrict__ Gmat, float* __restrict__ part)
{
    __shared__ float As[64 * 53];
    __shared__ float Gs[49 * 68];
    const int b = blockIdx.x;
    const int nt = b >> 7, ks = b & 127;
    const int n0 = nt * 64;
    const int cq0 = ks * 196;
    const int t = threadIdx.x;
    const int ng = t >> 2, pg = t & 3;   // ng: n row 0..63, pg: p quarter 0..3
    float acc[16];
    #pragma unroll
    for (int m = 0; m < 16; m++) acc[m] = 0.f;
    for (int kk = 0; kk < 4; kk++) {
        const int kb = cq0 + kk * 49;
        for (int i = t; i < 3136; i += 256) { int nr = i / 49, kc = i % 49; As[nr * 53 + kc] = x[(size_t)(n0 + nr) * CQ + kb + kc]; }
        for (int i = t; i < 2401; i += 256) { Gs[(i / 49) * 68 + (i % 49)] = Gmat[(size_t)kb * 49 + i]; }
        __syncthreads();
        // inline LayerNorm, 4 threads per row via quad shuffle reduce
        {
            float s = 0.f, ss = 0.f;
            for (int i = pg; i < 49; i += 4) { float v = As[ng * 53 + i]; s += v; ss += v * v; }
            s  += __shfl_xor(s, 1, 64);  s  += __shfl_xor(s, 2, 64);
            ss += __shfl_xor(ss, 1, 64); ss += __shfl_xor(ss, 2, 64);
            float mu = s * (1.f / 49.f);
            float var = ss * (1.f / 49.f) - mu * mu;
            float rs = 1.f / sqrtf(var + 1e-5f);
            for (int i = pg; i < 49; i += 4) As[ng * 53 + i] = (As[ng * 53 + i] - mu) * rs;
        }
        __syncthreads();
        for (int k = 0; k < 49; k++) {
            const float a = As[ng * 53 + k];
            const float* gp = &Gs[k * 68 + 16 * pg];
            float4 g0 = *(const float4*)(gp + 0);
            float4 g1 = *(const float4*)(gp + 4);
            float4 g2 = *(const float4*)(gp + 8);
            float4 g3 = *(const float4*)(gp + 12);
            acc[0]  += a * g0.x; acc[1]  += a * g0.y; acc[2]  += a * g0.z; acc[3]  += a * g0.w;
            acc[4]  += a * g1.x; acc[5]  += a * g1.y; acc[6]  += a * g1.z; acc[7]  += a * g1.w;
            acc[8]  += a * g2.x; acc[9]  += a * g2.y; acc[10] += a * g2.z; acc[11] += a * g2.w;
            acc[12] += a * g3.x; acc[13] += a * g3.y; acc[14] += a * g3.z; acc[15] += a * g3.w;
        }
        __syncthreads();
    }
    {
        const int n = n0 + ng;
        #pragma unroll
        for (int m = 0; m < 16; m++) {
            int p = 16 * pg + m;
            if (p < 49) part[(size_t)ks * CQ + (size_t)n * 49 + p] = acc[m];
        }
    }
}

// ---------------- K_cw2: reduce partials + Cb ----------------
__global__ __launch_bounds__(256) void kCw2(const float* __restrict__ part, const float* __restrict__ Cb,
                                            float* __restrict__ cw)
{
    int o = blockIdx.x * 256 + threadIdx.x;
    if (o >= CQ) return;
    int p = o % 49;
    float s = Cb[p];
    for (int ks = 0; ks < 128; ks++) s += part[(size_t)ks * CQ + o];
    cw[o] = s;
}

// ---------------- K_main: fused norms + logits + softmax + mask + VLAD + out ----------------
// c-half streaming: LDS ~71KB -> 2 blocks/CU.
__global__ __launch_bounds__(512, 4) void kMain(const float* __restrict__ x,
    const float* __restrict__ convw, const float* __restrict__ convb,
    const float* __restrict__ cwg, const float* __restrict__ cent, float* __restrict__ out)
{
    __shared__ float xH[49 * XHP];         // 50,960 B, one c-half transposed (l-major)
    __shared__ float lg[64 * 52];          // 13,312 B; logits -> mask in place
    __shared__ float ps[8 * 56];
    __shared__ float rn[49], cwl[49], smax[49], sinv[49];
    __shared__ float cb[64];
    __shared__ float pmx[392], psm[392];
    __shared__ float msL[64], ssq[64], scl[64];
    const int n = blockIdx.x;
    const int t = threadIdx.x;
    const int lane = t & 63;
    const int w = t >> 6;
    const float* xp = x + (size_t)n * CQ;

    if (t < 49) cwl[t] = cwg[n * 49 + t];
    if (t >= 64 && t < 128) cb[t - 64] = convb[t - 64];

    float a[8];
    #pragma unroll
    for (int j = 0; j < 8; j++) a[j] = 0.f;
    float rs_part = 0.f;

    // ---- pass 1: rn partials + logits accumulation over two c-halves ----
    for (int half = 0; half < 2; half++) {
        const int cbase = half * 256;
        __syncthreads();                       // protect xH from previous half's readers
        for (int idx = t; idx < 3136; idx += 512) {
            int l = idx % 49, cg = idx / 49;   // cg: column quad 0..63
            const float* src = xp + (size_t)(cbase + cg * 4) * 49 + l;
            float4 v;
            v.x = src[0]; v.y = src[49]; v.z = src[98]; v.w = src[147];
            *(float4*)&xH[l * XHP + cg * 4] = v;   // lane stride 260 words -> conflict-free-ish
        }
        __syncthreads();
        if (lane < 49) {                       // rn partial: wave w covers c-chunk [32w,32w+32)
            const float* row = &xH[lane * XHP + w * 32];
            float s = 0.f;
            #pragma unroll
            for (int c4 = 0; c4 < 8; c4++) {
                float4 v = *(const float4*)(row + c4 * 4);
                s += v.x * v.x + v.y * v.y + v.z * v.z + v.w * v.w;
            }
            rs_part += s;
        }
        {                                      // logits partial: wave w -> k octet, lane -> l
            const int lr = (lane < 49) ? lane : 48;
            const float* xrow = &xH[lr * XHP];
            #pragma unroll 4
            for (int c4 = 0; c4 < 64; c4++) {
                float4 xv = *(const float4*)(xrow + c4 * 4);
                #pragma unroll
                for (int j = 0; j < 8; j++) {
                    float4 wv = *(const float4*)&convw[(size_t)(w * 8 + j) * 512 + cbase + c4 * 4];
                    a[j] += wv.x * xv.x + wv.y * xv.y + wv.z * xv.z + wv.w * xv.w;
                }
            }
        }
    }
    if (lane < 49) ps[w * 56 + lane] = rs_part;
    __syncthreads();
    if (t < 49) {
        float s = 0.f;
        #pragma unroll
        for (int q = 0; q < 8; q++) s += ps[q * 56 + t];
        rn[t] = 1.f / fmaxf(sqrtf(s), 1e-12f);
    }
    __syncthreads();
    if (lane < 49) {
        float r = rn[lane];
        #pragma unroll
        for (int j = 0; j < 8; j++) lg[(w * 8 + j) * 52 + lane] = a[j] * r + cb[w * 8 + j];
    }
    __syncthreads();
    // ---- softmax over k per l; mask = sa*cw; msum; then *rn ----
    if (t < 392) {
        int l = t >> 3, kq = t & 7;
        float m = -3.402823466e38f;
        #pragma unroll
        for (int j = 0; j < 8; j++) m = fmaxf(m, lg[(kq * 8 + j) * 52 + l]);
        pmx[t] = m;
    }
    __syncthreads();
    if (t < 49) {
        float m = pmx[t * 8];
        #pragma unroll
        for (int q = 1; q < 8; q++) m = fmaxf(m, pmx[t * 8 + q]);
        smax[t] = m;
    }
    __syncthreads();
    if (t < 392) {
        int l = t >> 3, kq = t & 7;
        float m = smax[l], s = 0.f;
        #pragma unroll
        for (int j = 0; j < 8; j++) s += __expf(lg[(kq * 8 + j) * 52 + l] - m);
        psm[t] = s;
    }
    __syncthreads();
    if (t < 49) {
        float s = 0.f;
        #pragma unroll
        for (int q = 0; q < 8; q++) s += psm[t * 8 + q];
        sinv[t] = 1.f / s;
    }
    __syncthreads();
    if (t < 392) {
        int l = t >> 3, kq = t & 7;
        float m = smax[l], si = sinv[l] * cwl[l];
        #pragma unroll
        for (int j = 0; j < 8; j++) {
            int idx = (kq * 8 + j) * 52 + l;
            lg[idx] = __expf(lg[idx] - m) * si;   // mask_raw = sa*cw
        }
    }
    __syncthreads();
    if (t < 64) {
        float s = 0.f;
        for (int l = 0; l < 49; l++) s += lg[t * 52 + l];
        msL[t] = s;
    }
    __syncthreads();
    if (t < 392) {
        int l = t >> 3, kq = t & 7;
        float r = rn[l];
        #pragma unroll
        for (int j = 0; j < 8; j++) lg[(kq * 8 + j) * 52 + l] *= r;   // mk = sa*cw*rn
    }
    __syncthreads();
    // ---- VLAD half B first (xH still holds c 256..511), then reload half A ----
    const int c0 = lane * 4;
    float accB[8][4], accA[8][4];
    #pragma unroll
    for (int j = 0; j < 8; j++)
        #pragma unroll
        for (int ci = 0; ci < 4; ci++) { accB[j][ci] = 0.f; accA[j][ci] = 0.f; }
    #pragma unroll 7
    for (int l = 0; l < 49; l++) {
        float4 xv = *(const float4*)&xH[l * XHP + c0];
        #pragma unroll
        for (int j = 0; j < 8; j++) {
            float m = lg[(w * 8 + j) * 52 + l];
            accB[j][0] += m * xv.x; accB[j][1] += m * xv.y; accB[j][2] += m * xv.z; accB[j][3] += m * xv.w;
        }
    }
    __syncthreads();                       // all waves done reading half B
    for (int idx = t; idx < 3136; idx += 512) {
        int l = idx % 49, cg = idx / 49;
        const float* src = xp + (size_t)(cg * 4) * 49 + l;
        float4 v;
        v.x = src[0]; v.y = src[49]; v.z = src[98]; v.w = src[147];
        *(float4*)&xH[l * XHP + cg * 4] = v;
    }
    __syncthreads();
    #pragma unroll 7
    for (int l = 0; l < 49; l++) {
        float4 xv = *(const float4*)&xH[l * XHP + c0];
        #pragma unroll
        for (int j = 0; j < 8; j++) {
            float m = lg[(w * 8 + j) * 52 + l];
            accA[j][0] += m * xv.x; accA[j][1] += m * xv.y; accA[j][2] += m * xv.z; accA[j][3] += m * xv.w;
        }
    }
    // ---- epilogue: centroid subtract, intra-norm, global norm ----
    float ssr[8];
    #pragma unroll
    for (int j = 0; j < 8; j++) {
        int k = w * 8 + j;
        float ms = msL[k];
        float4 ca = *(const float4*)&cent[(size_t)k * 512 + c0];
        float4 cbv = *(const float4*)&cent[(size_t)k * 512 + 256 + c0];
        accA[j][0] -= ca.x * ms; accA[j][1] -= ca.y * ms; accA[j][2] -= ca.z * ms; accA[j][3] -= ca.w * ms;
        accB[j][0] -= cbv.x * ms; accB[j][1] -= cbv.y * ms; accB[j][2] -= cbv.z * ms; accB[j][3] -= cbv.w * ms;
        float s = 0.f;
        #pragma unroll
        for (int ci = 0; ci < 4; ci++) s += accA[j][ci] * accA[j][ci] + accB[j][ci] * accB[j][ci];
        ssr[j] = s;
    }
    #pragma unroll
    for (int j = 0; j < 8; j++)
        for (int off = 32; off >= 1; off >>= 1) ssr[j] += __shfl_xor(ssr[j], off, 64);
    if (lane == 0) {
        #pragma unroll
        for (int j = 0; j < 8; j++) ssq[w * 8 + j] = ssr[j];
    }
    __syncthreads();
    if (t < 64) {
        float nrm = sqrtf(ssq[t]);
        float inv = 1.f / fmaxf(nrm, 1e-12f);
        float sk = nrm * inv;
        float g = sk * sk;
        #pragma unroll
        for (int off = 32; off >= 1; off >>= 1) g += __shfl_xor(g, off, 64);
        scl[t] = inv * (1.f / fmaxf(sqrtf(g), 1e-12f));
    }
    __syncthreads();
    #pragma unroll
    for (int j = 0; j < 8; j++) {
        int k = w * 8 + j;
        float s2 = scl[k];
        float4 o1 = make_float4(accA[j][0] * s2, accA[j][1] * s2, accA[j][2] * s2, accA[j][3] * s2);
        float4 o2 = make_float4(accB[j][0] * s2, accB[j][1] * s2, accB[j][2] * s2, accB[j][3] * s2);
        *(float4*)&out[(size_t)n * 32768 + (size_t)k * 512 + c0] = o1;
        *(float4*)&out[(size_t)n * 32768 + (size_t)k * 512 + 256 + c0] = o2;
    }
}

extern "C" void kernel_launch(void* const* d_in, const int* in_sizes, int n_in,
                              void* d_out, int out_size, void* d_ws, size_t ws_size,
                              hipStream_t stream)
{
    const float* x     = (const float*)d_in[0];
    const float* cent  = (const float*)d_in[1];
    const float* convw = (const float*)d_in[2];
    const float* convb = (const float*)d_in[3];
    const float* lnw   = (const float*)d_in[4];
    const float* lnb   = (const float*)d_in[5];
    const float* c3w   = (const float*)d_in[6];
    const float* c3b   = (const float*)d_in[7];
    const float* c5w   = (const float*)d_in[8];
    const float* c5b   = (const float*)d_in[9];
    const float* c7w   = (const float*)d_in[10];
    const float* c7b   = (const float*)d_in[11];
    const float* dww   = (const float*)d_in[12];
    const float* dwb   = (const float*)d_in[13];
    const float* dhw   = (const float*)d_in[14];
    const float* dhb   = (const float*)d_in[15];
    const float* accw  = (const float*)d_in[16];
    const float* accb  = (const float*)d_in[17];
    float* out = (float*)d_out;

    char* ws = (char*)d_ws;
    float* Gmat = (float*)(ws);                 // 512*2401*4 = 4,917,248
    float* Gl   = (float*)(ws + 4917248);       // 512*49*4  = 100,352
    float* Cb   = (float*)(ws + 5017600);       // 256
    float* cw   = (float*)(ws + 5017856);       // 512*49*4  = 100,352
    float* part = (float*)(ws + 5118208);       // 128*25088*4 = 12,845,056 (end ~18MB)

    kG   <<<512,  256, 0, stream>>>(c3w, c5w, c7w, dww, dhw, accw, lnw, lnb, Gmat, Gl);
    kCb  <<<1,    64,  0, stream>>>(c3b, c5b, c7b, dww, dwb, dhw, dhb, accw, accb, Gl, Cb);
    kCw1 <<<1024, 256, 0, stream>>>(x, Gmat, part);
    kCw2 <<<98,   256, 0, stream>>>(part, Cb, cw);
    kMain<<<512,  512, 0, stream>>>(x, convw, convb, cw, cent, out);
}

// Round 5
// 283.554 us; speedup vs baseline: 1.0237x; 1.0237x over previous
//
#include <hip/hip_runtime.h>
#include <math.h>

#define NI 512
#define CC 512
#define KCL 64
#define HW49 49
#define CQ 25088   // 512*49
#define XHP 260    // xH row pitch (floats)
#define AP 260     // kCw1 A-tile pitch [q][n]
#define GP 68      // kCw1 G-tile pitch [q][p pad 64]

// Upsample matrix U[13][7], align_corners: even i -> 1 at i/2; odd i -> 0.5 at (i-1)/2,(i+1)/2
__device__ __forceinline__ float Uval(int i, int u) {
    if (i & 1) return (u == ((i - 1) >> 1) || u == ((i + 1) >> 1)) ? 0.5f : 0.0f;
    return (u == (i >> 1)) ? 1.0f : 0.0f;
}

// ---------------- K_G: build per-channel 49x49 operator (lnw folded in, lnb -> Gl) ----------------
__global__ __launch_bounds__(256) void kG(
    const float* __restrict__ c3w, const float* __restrict__ c5w, const float* __restrict__ c7w,
    const float* __restrict__ dww, const float* __restrict__ dhw, const float* __restrict__ accw,
    const float* __restrict__ lnw, const float* __restrict__ lnb,
    float* __restrict__ Gmat, float* __restrict__ Gl)
{
    const int c = blockIdx.x;
    const int t = threadIdx.x;
    __shared__ float dh[91], dw[91];
    __shared__ float Fh3[147], Fw3[147], Fh5[245], Fw5[245], Fh7[343], Fw7[343];
    __shared__ float wa3[9], wa5[25], wa7[49];
    __shared__ float Gtmp[2401];
    if (t < 91) dh[t] = dhw[t];
    if (t >= 128 && t < 219) dw[t - 128] = dww[t - 128];
    __syncthreads();
    for (int idx = t; idx < 147; idx += 256) {
        int oh = idx / 21, r = idx % 21, u = r / 3, dy = r % 3;
        float sh = 0.f, sw = 0.f;
        for (int i = 0; i < 13; i++) { int y = i - dy + 1; if (y >= 0 && y < 13) { float uu = Uval(i, u); sh += dh[oh * 13 + y] * uu; sw += dw[oh * 13 + y] * uu; } }
        Fh3[idx] = sh; Fw3[idx] = sw;
    }
    for (int idx = t; idx < 245; idx += 256) {
        int oh = idx / 35, r = idx % 35, u = r / 5, dy = r % 5;
        float sh = 0.f, sw = 0.f;
        for (int i = 0; i < 13; i++) { int y = i - dy + 2; if (y >= 0 && y < 13) { float uu = Uval(i, u); sh += dh[oh * 13 + y] * uu; sw += dw[oh * 13 + y] * uu; } }
        Fh5[idx] = sh; Fw5[idx] = sw;
    }
    for (int idx = t; idx < 343; idx += 256) {
        int oh = idx / 49, r = idx % 49, u = r / 7, dy = r % 7;
        float sh = 0.f, sw = 0.f;
        for (int i = 0; i < 13; i++) { int y = i - dy + 3; if (y >= 0 && y < 13) { float uu = Uval(i, u); sh += dh[oh * 13 + y] * uu; sw += dw[oh * 13 + y] * uu; } }
        Fh7[idx] = sh; Fw7[idx] = sw;
    }
    if (t < 9)               { float s = 0.f; for (int co = 0; co < 32; co++) s += accw[co]      * c3w[(size_t)(co * 512 + c) * 9  + t];        wa3[t] = s; }
    if (t >= 32 && t < 57)   { int q = t - 32; float s = 0.f; for (int co = 0; co < 32; co++) s += accw[32 + co] * c5w[(size_t)(co * 512 + c) * 25 + q]; wa5[q] = s; }
    if (t >= 64 && t < 113)  { int q = t - 64; float s = 0.f; for (int co = 0; co < 20; co++) s += accw[64 + co] * c7w[(size_t)(co * 512 + c) * 49 + q]; wa7[q] = s; }
    __syncthreads();
    for (int o = t; o < 2401; o += 256) {
        int q = o / 49, p = o % 49;
        int u = q / 7, v = q % 7, ow = p / 7, oh = p % 7;
        float acc = 0.f;
        #pragma unroll
        for (int dy = 0; dy < 3; dy++) { float fh = Fh3[(oh * 7 + u) * 3 + dy];
            #pragma unroll
            for (int dx = 0; dx < 3; dx++) acc += wa3[dy * 3 + dx] * fh * Fw3[(ow * 7 + v) * 3 + dx]; }
        #pragma unroll
        for (int dy = 0; dy < 5; dy++) { float fh = Fh5[(oh * 7 + u) * 5 + dy];
            #pragma unroll
            for (int dx = 0; dx < 5; dx++) acc += wa5[dy * 5 + dx] * fh * Fw5[(ow * 7 + v) * 5 + dx]; }
        #pragma unroll
        for (int dy = 0; dy < 7; dy++) { float fh = Fh7[(oh * 7 + u) * 7 + dy];
            #pragma unroll
            for (int dx = 0; dx < 7; dx++) acc += wa7[dy * 7 + dx] * fh * Fw7[(ow * 7 + v) * 7 + dx]; }
        Gtmp[o] = acc;
        Gmat[(size_t)c * 2401 + o] = acc * lnw[q];
    }
    __syncthreads();
    if (t < 49) {
        float s = 0.f;
        for (int q = 0; q < 49; q++) s += Gtmp[q * 49 + t] * lnb[q];
        Gl[c * 49 + t] = s;
    }
}

// ---------------- K_Cb: constant term of cw (incl. lnb fold via Gl) ----------------
__global__ void kCb(const float* __restrict__ c3b, const float* __restrict__ c5b, const float* __restrict__ c7b,
                    const float* __restrict__ dww, const float* __restrict__ dwb,
                    const float* __restrict__ dhw, const float* __restrict__ dhb,
                    const float* __restrict__ accw, const float* __restrict__ accb,
                    const float* __restrict__ Gl, float* __restrict__ Cb)
{
    __shared__ float A0s, A1s, Sdw[7], Sdh[7];
    int t = threadIdx.x;
    if (t == 0) {
        float a0 = 0.f, a1 = 0.f;
        for (int co = 0; co < 84; co++) {
            float aw = accw[co]; a0 += aw;
            float b = (co < 32) ? c3b[co] : ((co < 64) ? c5b[co - 32] : c7b[co - 64]);
            a1 += aw * b;
        }
        A0s = a0; A1s = a1;
    }
    if (t < 7)             { float s = 0.f; for (int xx = 0; xx < 13; xx++) s += dww[t * 13 + xx]; Sdw[t] = s; }
    if (t >= 8 && t < 15)  { int oh = t - 8; float s = 0.f; for (int y = 0; y < 13; y++) s += dhw[oh * 13 + y]; Sdh[oh] = s; }
    __syncthreads();
    if (t < 49) {
        int ow = t / 7, oh = t % 7;
        float g = 0.f;
        for (int c = 0; c < 512; c++) g += Gl[c * 49 + t];
        Cb[t] = A1s * Sdw[ow] * Sdh[oh] + A0s * (dwb[ow] * Sdh[oh] + dhb[oh]) + accb[0] + g;
    }
}

// ---------------- K_cw1: partial GEMM with inline LayerNorm ----------------
// 256-row n-tile, A transposed [q][n] in LDS; thread = 8n x 8p -> 4x b128 per 64 FMA.
// grid = 2 n-tiles x 128 ks-chunks (chunk = 4 channels).
__global__ __launch_bounds__(256) void kCw1(const float* __restrict__ x,
    const float* __restrict__ Gmat, float* __restrict__ part)
{
    __shared__ float As[49 * AP];   // [q][n], 50,960 B; reused as [256][49] out-stage
    __shared__ float Gs[49 * GP];   // [q][p pad 64], 13,328 B
    const int b = blockIdx.x;
    const int nt = b >> 7, ks = b & 127;
    const int n0 = nt * 256;
    const int t = threadIdx.x;
    const int tn = t >> 3;   // 0..31 -> rows 8*tn..8*tn+7
    const int tp = t & 7;    // p-octet: p = 8*tp..8*tp+7 (p<49 valid)
    float acc[8][8];
    #pragma unroll
    for (int j = 0; j < 8; j++)
        #pragma unroll
        for (int m = 0; m < 8; m++) acc[j][m] = 0.f;
    for (int kk = 0; kk < 4; kk++) {
        const int c = ks * 4 + kk;            // channel
        // stage A transposed: As[q][nr] = x[n0+nr][c][q]
        for (int i = t; i < 12544; i += 256) {
            int nr = i / 49, q = i - nr * 49;
            As[q * AP + nr] = x[(size_t)(n0 + nr) * CQ + (size_t)c * 49 + q];
        }
        // stage G rows q, cols p; pad cols 49..63 with 0
        for (int i = t; i < 2401; i += 256) {
            int q = i / 49, p = i - q * 49;
            Gs[q * GP + p] = Gmat[(size_t)c * 2401 + i];
        }
        for (int i = t; i < 735; i += 256) {
            int q = i / 15, pc = 49 + (i - q * 15);
            Gs[q * GP + pc] = 0.f;
        }
        __syncthreads();
        // LayerNorm per column n (thread t -> column t), conflict-free strided rows
        {
            float s = 0.f, ss = 0.f;
            for (int q = 0; q < 49; q++) { float v = As[q * AP + t]; s += v; ss += v * v; }
            float mu = s * (1.f / 49.f);
            float var = ss * (1.f / 49.f) - mu * mu;
            float rs = 1.f / sqrtf(var + 1e-5f);
            for (int q = 0; q < 49; q++) As[q * AP + t] = (As[q * AP + t] - mu) * rs;
        }
        __syncthreads();
        for (int q = 0; q < 49; q++) {
            float4 a0 = *(const float4*)&As[q * AP + tn * 8];
            float4 a1 = *(const float4*)&As[q * AP + tn * 8 + 4];
            float4 g0 = *(const float4*)&Gs[q * GP + tp * 8];
            float4 g1 = *(const float4*)&Gs[q * GP + tp * 8 + 4];
            float av[8] = {a0.x, a0.y, a0.z, a0.w, a1.x, a1.y, a1.z, a1.w};
            float gv[8] = {g0.x, g0.y, g0.z, g0.w, g1.x, g1.y, g1.z, g1.w};
            #pragma unroll
            for (int j = 0; j < 8; j++)
                #pragma unroll
                for (int m = 0; m < 8; m++) acc[j][m] += av[j] * gv[m];
        }
        __syncthreads();
    }
    // stage results to LDS [256][49] then coalesced global write
    #pragma unroll
    for (int j = 0; j < 8; j++) {
        #pragma unroll
        for (int m = 0; m < 8; m++) {
            int p = tp * 8 + m;
            if (p < 49) As[(tn * 8 + j) * 49 + p] = acc[j][m];
        }
    }
    __syncthreads();
    {
        float* dst = part + (size_t)ks * CQ + (size_t)n0 * 49;
        for (int i = t; i < 12544; i += 256) dst[i] = As[i];
    }
}

// ---------------- K_main: cw-reduce + norms + logits + softmax + mask + VLAD + out ----------------
// c-half streaming: LDS ~71KB -> 2 blocks/CU; VGPR cap 128 (no spill).
__global__ __launch_bounds__(512, 2) void kMain(const float* __restrict__ x,
    const float* __restrict__ convw, const float* __restrict__ convb,
    const float* __restrict__ part, const float* __restrict__ Cbg,
    const float* __restrict__ cent, float* __restrict__ out)
{
    __shared__ float xH[49 * XHP];         // 50,960 B, one c-half transposed (l-major)
    __shared__ float lg[64 * 52];          // 13,312 B; logits -> mask in place
    __shared__ float ps[8 * 56];
    __shared__ float rn[49], cwl[49], smax[49], sinv[49];
    __shared__ float cb[64];
    __shared__ float pmx[392], psm[392];
    __shared__ float msL[64], ssq[64], scl[64];
    const int n = blockIdx.x;
    const int t = threadIdx.x;
    const int lane = t & 63;
    const int w = t >> 6;
    const float* xp = x + (size_t)n * CQ;

    // ---- prologue: cw[n][p] = Cb[p] + sum_ks part[ks][n][p] ----
    if (t < 392) {
        int p = t >> 3, q = t & 7;
        const float* bp = part + (size_t)n * 49 + p;
        float s = 0.f;
        for (int ks = q * 16; ks < q * 16 + 16; ks++) s += bp[(size_t)ks * CQ];
        psm[t] = s;
    }
    if (t >= 448) cb[t - 448] = convb[t - 448];
    __syncthreads();
    if (t < 49) {
        float s = Cbg[t];
        #pragma unroll
        for (int q = 0; q < 8; q++) s += psm[t * 8 + q];
        cwl[t] = s;
    }

    float a[8];
    #pragma unroll
    for (int j = 0; j < 8; j++) a[j] = 0.f;
    float rs_part = 0.f;

    // ---- pass 1: rn partials + logits accumulation over two c-halves ----
    for (int half = 0; half < 2; half++) {
        const int cbase = half * 256;
        __syncthreads();
        for (int idx = t; idx < 3136; idx += 512) {
            int l = idx % 49, cg = idx / 49;
            const float* src = xp + (size_t)(cbase + cg * 4) * 49 + l;
            float4 v;
            v.x = src[0]; v.y = src[49]; v.z = src[98]; v.w = src[147];
            *(float4*)&xH[l * XHP + cg * 4] = v;
        }
        __syncthreads();
        if (lane < 49) {
            const float* row = &xH[lane * XHP + w * 32];
            float s = 0.f;
            #pragma unroll
            for (int c4 = 0; c4 < 8; c4++) {
                float4 v = *(const float4*)(row + c4 * 4);
                s += v.x * v.x + v.y * v.y + v.z * v.z + v.w * v.w;
            }
            rs_part += s;
        }
        {
            const int lr = (lane < 49) ? lane : 48;
            const float* xrow = &xH[lr * XHP];
            #pragma unroll 4
            for (int c4 = 0; c4 < 64; c4++) {
                float4 xv = *(const float4*)(xrow + c4 * 4);
                #pragma unroll
                for (int j = 0; j < 8; j++) {
                    float4 wv = *(const float4*)&convw[(size_t)(w * 8 + j) * 512 + cbase + c4 * 4];
                    a[j] += wv.x * xv.x + wv.y * xv.y + wv.z * xv.z + wv.w * xv.w;
                }
            }
        }
    }
    if (lane < 49) ps[w * 56 + lane] = rs_part;
    __syncthreads();
    if (t < 49) {
        float s = 0.f;
        #pragma unroll
        for (int q = 0; q < 8; q++) s += ps[q * 56 + t];
        rn[t] = 1.f / fmaxf(sqrtf(s), 1e-12f);
    }
    __syncthreads();
    if (lane < 49) {
        float r = rn[lane];
        #pragma unroll
        for (int j = 0; j < 8; j++) lg[(w * 8 + j) * 52 + lane] = a[j] * r + cb[w * 8 + j];
    }
    __syncthreads();
    // ---- softmax over k per l; mask = sa*cw; msum; then *rn ----
    if (t < 392) {
        int l = t >> 3, kq = t & 7;
        float m = -3.402823466e38f;
        #pragma unroll
        for (int j = 0; j < 8; j++) m = fmaxf(m, lg[(kq * 8 + j) * 52 + l]);
        pmx[t] = m;
    }
    __syncthreads();
    if (t < 49) {
        float m = pmx[t * 8];
        #pragma unroll
        for (int q = 1; q < 8; q++) m = fmaxf(m, pmx[t * 8 + q]);
        smax[t] = m;
    }
    __syncthreads();
    if (t < 392) {
        int l = t >> 3, kq = t & 7;
        float m = smax[l], s = 0.f;
        #pragma unroll
        for (int j = 0; j < 8; j++) s += __expf(lg[(kq * 8 + j) * 52 + l] - m);
        psm[t] = s;
    }
    __syncthreads();
    if (t < 49) {
        float s = 0.f;
        #pragma unroll
        for (int q = 0; q < 8; q++) s += psm[t * 8 + q];
        sinv[t] = 1.f / s;
    }
    __syncthreads();
    if (t < 392) {
        int l = t >> 3, kq = t & 7;
        float m = smax[l], si = sinv[l] * cwl[l];
        #pragma unroll
        for (int j = 0; j < 8; j++) {
            int idx = (kq * 8 + j) * 52 + l;
            lg[idx] = __expf(lg[idx] - m) * si;   // mask_raw = sa*cw
        }
    }
    __syncthreads();
    if (t < 64) {
        float s = 0.f;
        for (int l = 0; l < 49; l++) s += lg[t * 52 + l];
        msL[t] = s;
    }
    __syncthreads();
    if (t < 392) {
        int l = t >> 3, kq = t & 7;
        float r = rn[l];
        #pragma unroll
        for (int j = 0; j < 8; j++) lg[(kq * 8 + j) * 52 + l] *= r;   // mk = sa*cw*rn
    }
    __syncthreads();
    // ---- VLAD half B first (xH holds c 256..511), then reload half A ----
    const int c0 = lane * 4;
    float accB[8][4], accA[8][4];
    #pragma unroll
    for (int j = 0; j < 8; j++)
        #pragma unroll
        for (int ci = 0; ci < 4; ci++) { accB[j][ci] = 0.f; accA[j][ci] = 0.f; }
    #pragma unroll 7
    for (int l = 0; l < 49; l++) {
        float4 xv = *(const float4*)&xH[l * XHP + c0];
        #pragma unroll
        for (int j = 0; j < 8; j++) {
            float m = lg[(w * 8 + j) * 52 + l];
            accB[j][0] += m * xv.x; accB[j][1] += m * xv.y; accB[j][2] += m * xv.z; accB[j][3] += m * xv.w;
        }
    }
    __syncthreads();
    for (int idx = t; idx < 3136; idx += 512) {
        int l = idx % 49, cg = idx / 49;
        const float* src = xp + (size_t)(cg * 4) * 49 + l;
        float4 v;
        v.x = src[0]; v.y = src[49]; v.z = src[98]; v.w = src[147];
        *(float4*)&xH[l * XHP + cg * 4] = v;
    }
    __syncthreads();
    #pragma unroll 7
    for (int l = 0; l < 49; l++) {
        float4 xv = *(const float4*)&xH[l * XHP + c0];
        #pragma unroll
        for (int j = 0; j < 8; j++) {
            float m = lg[(w * 8 + j) * 52 + l];
            accA[j][0] += m * xv.x; accA[j][1] += m * xv.y; accA[j][2] += m * xv.z; accA[j][3] += m * xv.w;
        }
    }
    // ---- epilogue: centroid subtract, intra-norm, global norm ----
    float ssr[8];
    #pragma unroll
    for (int j = 0; j < 8; j++) {
        int k = w * 8 + j;
        float ms = msL[k];
        float4 ca = *(const float4*)&cent[(size_t)k * 512 + c0];
        float4 cbv = *(const float4*)&cent[(size_t)k * 512 + 256 + c0];
        accA[j][0] -= ca.x * ms; accA[j][1] -= ca.y * ms; accA[j][2] -= ca.z * ms; accA[j][3] -= ca.w * ms;
        accB[j][0] -= cbv.x * ms; accB[j][1] -= cbv.y * ms; accB[j][2] -= cbv.z * ms; accB[j][3] -= cbv.w * ms;
        float s = 0.f;
        #pragma unroll
        for (int ci = 0; ci < 4; ci++) s += accA[j][ci] * accA[j][ci] + accB[j][ci] * accB[j][ci];
        ssr[j] = s;
    }
    #pragma unroll
    for (int j = 0; j < 8; j++)
        for (int off = 32; off >= 1; off >>= 1) ssr[j] += __shfl_xor(ssr[j], off, 64);
    if (lane == 0) {
        #pragma unroll
        for (int j = 0; j < 8; j++) ssq[w * 8 + j] = ssr[j];
    }
    __syncthreads();
    if (t < 64) {
        float nrm = sqrtf(ssq[t]);
        float inv = 1.f / fmaxf(nrm, 1e-12f);
        float sk = nrm * inv;
        float g = sk * sk;
        #pragma unroll
        for (int off = 32; off >= 1; off >>= 1) g += __shfl_xor(g, off, 64);
        scl[t] = inv * (1.f / fmaxf(sqrtf(g), 1e-12f));
    }
    __syncthreads();
    #pragma unroll
    for (int j = 0; j < 8; j++) {
        int k = w * 8 + j;
        float s2 = scl[k];
        float4 o1 = make_float4(accA[j][0] * s2, accA[j][1] * s2, accA[j][2] * s2, accA[j][3] * s2);
        float4 o2 = make_float4(accB[j][0] * s2, accB[j][1] * s2, accB[j][2] * s2, accB[j][3] * s2);
        *(float4*)&out[(size_t)n * 32768 + (size_t)k * 512 + c0] = o1;
        *(float4*)&out[(size_t)n * 32768 + (size_t)k * 512 + 256 + c0] = o2;
    }
}

extern "C" void kernel_launch(void* const* d_in, const int* in_sizes, int n_in,
                              void* d_out, int out_size, void* d_ws, size_t ws_size,
                              hipStream_t stream)
{
    const float* x     = (const float*)d_in[0];
    const float* cent  = (const float*)d_in[1];
    const float* convw = (const float*)d_in[2];
    const float* convb = (const float*)d_in[3];
    const float* lnw   = (const float*)d_in[4];
    const float* lnb   = (const float*)d_in[5];
    const float* c3w   = (const float*)d_in[6];
    const float* c3b   = (const float*)d_in[7];
    const float* c5w   = (const float*)d_in[8];
    const float* c5b   = (const float*)d_in[9];
    const float* c7w   = (const float*)d_in[10];
    const float* c7b   = (const float*)d_in[11];
    const float* dww   = (const float*)d_in[12];
    const float* dwb   = (const float*)d_in[13];
    const float* dhw   = (const float*)d_in[14];
    const float* dhb   = (const float*)d_in[15];
    const float* accw  = (const float*)d_in[16];
    const float* accb  = (const float*)d_in[17];
    float* out = (float*)d_out;

    char* ws = (char*)d_ws;
    float* Gmat = (float*)(ws);                 // 512*2401*4 = 4,917,248
    float* Gl   = (float*)(ws + 4917248);       // 512*49*4  = 100,352
    float* Cb   = (float*)(ws + 5017600);       // 256
    float* part = (float*)(ws + 5017856);       // 128*25088*4 = 12,845,056 (end ~17.9MB)

    kG   <<<512, 256, 0, stream>>>(c3w, c5w, c7w, dww, dhw, accw, lnw, lnb, Gmat, Gl);
    kCb  <<<1,   64,  0, stream>>>(c3b, c5b, c7b, dww, dwb, dhw, dhb, accw, accb, Gl, Cb);
    kCw1 <<<256, 256, 0, stream>>>(x, Gmat, part);
    kMain<<<512, 512, 0, stream>>>(x, convw, convb, part, Cb, cent, out);
}

// Round 6
// 220.792 us; speedup vs baseline: 1.3147x; 1.2843x over previous
//
#include <hip/hip_runtime.h>
#include <math.h>

#define NI 512
#define CC 512
#define KCL 64
#define HW49 49
#define CQ 25088   // 512*49
#define XHP 260    // xH row pitch (floats)
#define AP 260     // kCw1 A-tile pitch [q][n]
#define GP 68      // kCw1 G-tile pitch [q][p pad 64]
#define NKS 256    // cw partial slices (2 channels each)

// Upsample matrix U[13][7], align_corners: even i -> 1 at i/2; odd i -> 0.5 at (i-1)/2,(i+1)/2
__device__ __forceinline__ float Uval(int i, int u) {
    if (i & 1) return (u == ((i - 1) >> 1) || u == ((i + 1) >> 1)) ? 0.5f : 0.0f;
    return (u == (i >> 1)) ? 1.0f : 0.0f;
}

// ---------------- K_G: build per-channel 49x49 operator (lnw folded in, lnb -> Gl) ----------------
__global__ __launch_bounds__(256) void kG(
    const float* __restrict__ c3w, const float* __restrict__ c5w, const float* __restrict__ c7w,
    const float* __restrict__ dww, const float* __restrict__ dhw, const float* __restrict__ accw,
    const float* __restrict__ lnw, const float* __restrict__ lnb,
    float* __restrict__ Gmat, float* __restrict__ Gl)
{
    const int c = blockIdx.x;
    const int t = threadIdx.x;
    __shared__ float dh[91], dw[91];
    __shared__ float Fh3[147], Fw3[147], Fh5[245], Fw5[245], Fh7[343], Fw7[343];
    __shared__ float wa3[9], wa5[25], wa7[49];
    __shared__ float Gtmp[2401];
    if (t < 91) dh[t] = dhw[t];
    if (t >= 128 && t < 219) dw[t - 128] = dww[t - 128];
    __syncthreads();
    for (int idx = t; idx < 147; idx += 256) {
        int oh = idx / 21, r = idx % 21, u = r / 3, dy = r % 3;
        float sh = 0.f, sw = 0.f;
        for (int i = 0; i < 13; i++) { int y = i - dy + 1; if (y >= 0 && y < 13) { float uu = Uval(i, u); sh += dh[oh * 13 + y] * uu; sw += dw[oh * 13 + y] * uu; } }
        Fh3[idx] = sh; Fw3[idx] = sw;
    }
    for (int idx = t; idx < 245; idx += 256) {
        int oh = idx / 35, r = idx % 35, u = r / 5, dy = r % 5;
        float sh = 0.f, sw = 0.f;
        for (int i = 0; i < 13; i++) { int y = i - dy + 2; if (y >= 0 && y < 13) { float uu = Uval(i, u); sh += dh[oh * 13 + y] * uu; sw += dw[oh * 13 + y] * uu; } }
        Fh5[idx] = sh; Fw5[idx] = sw;
    }
    for (int idx = t; idx < 343; idx += 256) {
        int oh = idx / 49, r = idx % 49, u = r / 7, dy = r % 7;
        float sh = 0.f, sw = 0.f;
        for (int i = 0; i < 13; i++) { int y = i - dy + 3; if (y >= 0 && y < 13) { float uu = Uval(i, u); sh += dh[oh * 13 + y] * uu; sw += dw[oh * 13 + y] * uu; } }
        Fh7[idx] = sh; Fw7[idx] = sw;
    }
    if (t < 9)               { float s = 0.f; for (int co = 0; co < 32; co++) s += accw[co]      * c3w[(size_t)(co * 512 + c) * 9  + t];        wa3[t] = s; }
    if (t >= 32 && t < 57)   { int q = t - 32; float s = 0.f; for (int co = 0; co < 32; co++) s += accw[32 + co] * c5w[(size_t)(co * 512 + c) * 25 + q]; wa5[q] = s; }
    if (t >= 64 && t < 113)  { int q = t - 64; float s = 0.f; for (int co = 0; co < 20; co++) s += accw[64 + co] * c7w[(size_t)(co * 512 + c) * 49 + q]; wa7[q] = s; }
    __syncthreads();
    for (int o = t; o < 2401; o += 256) {
        int q = o / 49, p = o % 49;
        int u = q / 7, v = q % 7, ow = p / 7, oh = p % 7;
        float acc = 0.f;
        #pragma unroll
        for (int dy = 0; dy < 3; dy++) { float fh = Fh3[(oh * 7 + u) * 3 + dy];
            #pragma unroll
            for (int dx = 0; dx < 3; dx++) acc += wa3[dy * 3 + dx] * fh * Fw3[(ow * 7 + v) * 3 + dx]; }
        #pragma unroll
        for (int dy = 0; dy < 5; dy++) { float fh = Fh5[(oh * 7 + u) * 5 + dy];
            #pragma unroll
            for (int dx = 0; dx < 5; dx++) acc += wa5[dy * 5 + dx] * fh * Fw5[(ow * 7 + v) * 5 + dx]; }
        #pragma unroll
        for (int dy = 0; dy < 7; dy++) { float fh = Fh7[(oh * 7 + u) * 7 + dy];
            #pragma unroll
            for (int dx = 0; dx < 7; dx++) acc += wa7[dy * 7 + dx] * fh * Fw7[(ow * 7 + v) * 7 + dx]; }
        Gtmp[o] = acc;
        Gmat[(size_t)c * 2401 + o] = acc * lnw[q];
    }
    __syncthreads();
    if (t < 49) {
        float s = 0.f;
        for (int q = 0; q < 49; q++) s += Gtmp[q * 49 + t] * lnb[q];
        Gl[c * 49 + t] = s;
    }
}

// ---------------- K_Cb: constant term of cw (incl. lnb fold via Gl) ----------------
__global__ void kCb(const float* __restrict__ c3b, const float* __restrict__ c5b, const float* __restrict__ c7b,
                    const float* __restrict__ dww, const float* __restrict__ dwb,
                    const float* __restrict__ dhw, const float* __restrict__ dhb,
                    const float* __restrict__ accw, const float* __restrict__ accb,
                    const float* __restrict__ Gl, float* __restrict__ Cb)
{
    __shared__ float A0s, A1s, Sdw[7], Sdh[7];
    int t = threadIdx.x;
    if (t == 0) {
        float a0 = 0.f, a1 = 0.f;
        for (int co = 0; co < 84; co++) {
            float aw = accw[co]; a0 += aw;
            float b = (co < 32) ? c3b[co] : ((co < 64) ? c5b[co - 32] : c7b[co - 64]);
            a1 += aw * b;
        }
        A0s = a0; A1s = a1;
    }
    if (t < 7)             { float s = 0.f; for (int xx = 0; xx < 13; xx++) s += dww[t * 13 + xx]; Sdw[t] = s; }
    if (t >= 8 && t < 15)  { int oh = t - 8; float s = 0.f; for (int y = 0; y < 13; y++) s += dhw[oh * 13 + y]; Sdh[oh] = s; }
    __syncthreads();
    if (t < 49) {
        int ow = t / 7, oh = t % 7;
        float g = 0.f;
        for (int c = 0; c < 512; c++) g += Gl[c * 49 + t];
        Cb[t] = A1s * Sdw[ow] * Sdh[oh] + A0s * (dwb[ow] * Sdh[oh] + dhb[oh]) + accb[0] + g;
    }
}

// ---------------- K_cw1: partial GEMM with inline LayerNorm ----------------
// 256-row n-tile, A transposed [q][n] in LDS; thread = 8n x 8p -> 4x b128 per 64 FMA.
// grid = 2 n-tiles x 256 ks-chunks (chunk = 2 channels) -> 2 blocks/CU.
__global__ __launch_bounds__(256) void kCw1(const float* __restrict__ x,
    const float* __restrict__ Gmat, float* __restrict__ part)
{
    __shared__ float As[49 * AP];   // [q][n], 50,960 B; reused as [256][49] out-stage
    __shared__ float Gs[49 * GP];   // [q][p pad 64], 13,328 B
    const int b = blockIdx.x;
    const int nt = b >> 8, ks = b & 255;
    const int n0 = nt * 256;
    const int t = threadIdx.x;
    const int tn = t >> 3;   // 0..31 -> rows 8*tn..8*tn+7
    const int tp = t & 7;    // p-octet: p = 8*tp..8*tp+7 (p<49 valid)
    float acc[8][8];
    #pragma unroll
    for (int j = 0; j < 8; j++)
        #pragma unroll
        for (int m = 0; m < 8; m++) acc[j][m] = 0.f;
    for (int kk = 0; kk < 2; kk++) {
        const int c = ks * 2 + kk;            // channel
        // stage A transposed: As[q][nr] = x[n0+nr][c][q]
        for (int i = t; i < 12544; i += 256) {
            int nr = i / 49, q = i - nr * 49;
            As[q * AP + nr] = x[(size_t)(n0 + nr) * CQ + (size_t)c * 49 + q];
        }
        // stage G rows q, cols p; pad cols 49..63 with 0
        for (int i = t; i < 2401; i += 256) {
            int q = i / 49, p = i - q * 49;
            Gs[q * GP + p] = Gmat[(size_t)c * 2401 + i];
        }
        for (int i = t; i < 735; i += 256) {
            int q = i / 15, pc = 49 + (i - q * 15);
            Gs[q * GP + pc] = 0.f;
        }
        __syncthreads();
        // LayerNorm per column n (thread t -> column t), conflict-free strided rows
        {
            float s = 0.f, ss = 0.f;
            for (int q = 0; q < 49; q++) { float v = As[q * AP + t]; s += v; ss += v * v; }
            float mu = s * (1.f / 49.f);
            float var = ss * (1.f / 49.f) - mu * mu;
            float rs = 1.f / sqrtf(var + 1e-5f);
            for (int q = 0; q < 49; q++) As[q * AP + t] = (As[q * AP + t] - mu) * rs;
        }
        __syncthreads();
        for (int q = 0; q < 49; q++) {
            float4 a0 = *(const float4*)&As[q * AP + tn * 8];
            float4 a1 = *(const float4*)&As[q * AP + tn * 8 + 4];
            float4 g0 = *(const float4*)&Gs[q * GP + tp * 8];
            float4 g1 = *(const float4*)&Gs[q * GP + tp * 8 + 4];
            float av[8] = {a0.x, a0.y, a0.z, a0.w, a1.x, a1.y, a1.z, a1.w};
            float gv[8] = {g0.x, g0.y, g0.z, g0.w, g1.x, g1.y, g1.z, g1.w};
            #pragma unroll
            for (int j = 0; j < 8; j++)
                #pragma unroll
                for (int m = 0; m < 8; m++) acc[j][m] += av[j] * gv[m];
        }
        __syncthreads();
    }
    // stage results to LDS [256][49] then coalesced global write
    #pragma unroll
    for (int j = 0; j < 8; j++) {
        #pragma unroll
        for (int m = 0; m < 8; m++) {
            int p = tp * 8 + m;
            if (p < 49) As[(tn * 8 + j) * 49 + p] = acc[j][m];
        }
    }
    __syncthreads();
    {
        float* dst = part + (size_t)ks * CQ + (size_t)n0 * 49;
        for (int i = t; i < 12544; i += 256) dst[i] = As[i];
    }
}

// ---------------- K_main: cw-reduce + norms + logits + softmax + mask + VLAD + out ----------------
// c-half streaming: LDS ~71KB -> 2 blocks/CU; VGPR cap 128 (no spill); convw via scalar loads.
__global__ __launch_bounds__(512, 2) void kMain(const float* __restrict__ x,
    const float* __restrict__ convw, const float* __restrict__ convb,
    const float* __restrict__ part, const float* __restrict__ Cbg,
    const float* __restrict__ cent, float* __restrict__ out)
{
    __shared__ float xH[49 * XHP];         // 50,960 B, one c-half transposed (l-major)
    __shared__ float lg[64 * 52];          // 13,312 B; logits -> mask in place
    __shared__ float ps[8 * 56];
    __shared__ float rn[49], cwl[49], smax[49], sinv[49];
    __shared__ float cb[64];
    __shared__ float pmx[392], psm[392];
    __shared__ float msL[64], ssq[64], scl[64];
    const int n = blockIdx.x;
    const int t = threadIdx.x;
    const int lane = t & 63;
    const int w = t >> 6;
    const float* xp = x + (size_t)n * CQ;

    // ---- prologue: cw[n][p] = Cb[p] + sum_ks part[ks][n][p] ----
    if (t < 392) {
        int p = t >> 3, q = t & 7;
        const float* bp = part + (size_t)n * 49 + p;
        float s = 0.f;
        for (int ks = q * 32; ks < q * 32 + 32; ks++) s += bp[(size_t)ks * CQ];
        psm[t] = s;
    }
    if (t >= 448) cb[t - 448] = convb[t - 448];
    __syncthreads();
    if (t < 49) {
        float s = Cbg[t];
        #pragma unroll
        for (int q = 0; q < 8; q++) s += psm[t * 8 + q];
        cwl[t] = s;
    }

    float a[8];
    #pragma unroll
    for (int j = 0; j < 8; j++) a[j] = 0.f;
    float rs_part = 0.f;
    const int kw = __builtin_amdgcn_readfirstlane(w);   // wave-uniform -> scalar address path

    // ---- pass 1: rn partials + logits accumulation over two c-halves ----
    for (int half = 0; half < 2; half++) {
        const int cbase = half * 256;
        __syncthreads();
        for (int idx = t; idx < 3136; idx += 512) {
            int l = idx % 49, cg = idx / 49;
            const float* src = xp + (size_t)(cbase + cg * 4) * 49 + l;
            float4 v;
            v.x = src[0]; v.y = src[49]; v.z = src[98]; v.w = src[147];
            *(float4*)&xH[l * XHP + cg * 4] = v;
        }
        __syncthreads();
        if (lane < 49) {
            const float* row = &xH[lane * XHP + kw * 32];
            float s = 0.f;
            #pragma unroll
            for (int c4 = 0; c4 < 8; c4++) {
                float4 v = *(const float4*)(row + c4 * 4);
                s += v.x * v.x + v.y * v.y + v.z * v.z + v.w * v.w;
            }
            rs_part += s;
        }
        {
            const int lr = (lane < 49) ? lane : 48;
            const float* xrow = &xH[lr * XHP];
            const float* wb = convw + (size_t)(kw * 8) * 512 + cbase;   // SGPR base
            #pragma unroll 4
            for (int c4 = 0; c4 < 64; c4++) {
                float4 xv = *(const float4*)(xrow + c4 * 4);
                #pragma unroll
                for (int j = 0; j < 8; j++) {
                    float4 wv = *(const float4*)&wb[(size_t)j * 512 + c4 * 4];
                    a[j] += wv.x * xv.x + wv.y * xv.y + wv.z * xv.z + wv.w * xv.w;
                }
            }
        }
    }
    if (lane < 49) ps[kw * 56 + lane] = rs_part;
    __syncthreads();
    if (t < 49) {
        float s = 0.f;
        #pragma unroll
        for (int q = 0; q < 8; q++) s += ps[q * 56 + t];
        rn[t] = 1.f / fmaxf(sqrtf(s), 1e-12f);
    }
    __syncthreads();
    if (lane < 49) {
        float r = rn[lane];
        #pragma unroll
        for (int j = 0; j < 8; j++) lg[(kw * 8 + j) * 52 + lane] = a[j] * r + cb[kw * 8 + j];
    }
    __syncthreads();
    // ---- softmax over k per l; mask = sa*cw; msum; then *rn ----
    if (t < 392) {
        int l = t >> 3, kq = t & 7;
        float m = -3.402823466e38f;
        #pragma unroll
        for (int j = 0; j < 8; j++) m = fmaxf(m, lg[(kq * 8 + j) * 52 + l]);
        pmx[t] = m;
    }
    __syncthreads();
    if (t < 49) {
        float m = pmx[t * 8];
        #pragma unroll
        for (int q = 1; q < 8; q++) m = fmaxf(m, pmx[t * 8 + q]);
        smax[t] = m;
    }
    __syncthreads();
    if (t < 392) {
        int l = t >> 3, kq = t & 7;
        float m = smax[l], s = 0.f;
        #pragma unroll
        for (int j = 0; j < 8; j++) s += __expf(lg[(kq * 8 + j) * 52 + l] - m);
        psm[t] = s;
    }
    __syncthreads();
    if (t < 49) {
        float s = 0.f;
        #pragma unroll
        for (int q = 0; q < 8; q++) s += psm[t * 8 + q];
        sinv[t] = 1.f / s;
    }
    __syncthreads();
    if (t < 392) {
        int l = t >> 3, kq = t & 7;
        float m = smax[l], si = sinv[l] * cwl[l];
        #pragma unroll
        for (int j = 0; j < 8; j++) {
            int idx = (kq * 8 + j) * 52 + l;
            lg[idx] = __expf(lg[idx] - m) * si;   // mask_raw = sa*cw
        }
    }
    __syncthreads();
    if (t < 64) {
        float s = 0.f;
        for (int l = 0; l < 49; l++) s += lg[t * 52 + l];
        msL[t] = s;
    }
    __syncthreads();
    if (t < 392) {
        int l = t >> 3, kq = t & 7;
        float r = rn[l];
        #pragma unroll
        for (int j = 0; j < 8; j++) lg[(kq * 8 + j) * 52 + l] *= r;   // mk = sa*cw*rn
    }
    __syncthreads();
    // ---- VLAD half B first (xH holds c 256..511), then reload half A ----
    const int c0 = lane * 4;
    float accB[8][4], accA[8][4];
    #pragma unroll
    for (int j = 0; j < 8; j++)
        #pragma unroll
        for (int ci = 0; ci < 4; ci++) { accB[j][ci] = 0.f; accA[j][ci] = 0.f; }
    #pragma unroll 7
    for (int l = 0; l < 49; l++) {
        float4 xv = *(const float4*)&xH[l * XHP + c0];
        #pragma unroll
        for (int j = 0; j < 8; j++) {
            float m = lg[(kw * 8 + j) * 52 + l];
            accB[j][0] += m * xv.x; accB[j][1] += m * xv.y; accB[j][2] += m * xv.z; accB[j][3] += m * xv.w;
        }
    }
    __syncthreads();
    for (int idx = t; idx < 3136; idx += 512) {
        int l = idx % 49, cg = idx / 49;
        const float* src = xp + (size_t)(cg * 4) * 49 + l;
        float4 v;
        v.x = src[0]; v.y = src[49]; v.z = src[98]; v.w = src[147];
        *(float4*)&xH[l * XHP + cg * 4] = v;
    }
    __syncthreads();
    #pragma unroll 7
    for (int l = 0; l < 49; l++) {
        float4 xv = *(const float4*)&xH[l * XHP + c0];
        #pragma unroll
        for (int j = 0; j < 8; j++) {
            float m = lg[(kw * 8 + j) * 52 + l];
            accA[j][0] += m * xv.x; accA[j][1] += m * xv.y; accA[j][2] += m * xv.z; accA[j][3] += m * xv.w;
        }
    }
    // ---- epilogue: centroid subtract, intra-norm, global norm ----
    float ssr[8];
    #pragma unroll
    for (int j = 0; j < 8; j++) {
        int k = kw * 8 + j;
        float ms = msL[k];
        float4 ca = *(const float4*)&cent[(size_t)k * 512 + c0];
        float4 cbv = *(const float4*)&cent[(size_t)k * 512 + 256 + c0];
        accA[j][0] -= ca.x * ms; accA[j][1] -= ca.y * ms; accA[j][2] -= ca.z * ms; accA[j][3] -= ca.w * ms;
        accB[j][0] -= cbv.x * ms; accB[j][1] -= cbv.y * ms; accB[j][2] -= cbv.z * ms; accB[j][3] -= cbv.w * ms;
        float s = 0.f;
        #pragma unroll
        for (int ci = 0; ci < 4; ci++) s += accA[j][ci] * accA[j][ci] + accB[j][ci] * accB[j][ci];
        ssr[j] = s;
    }
    #pragma unroll
    for (int j = 0; j < 8; j++)
        for (int off = 32; off >= 1; off >>= 1) ssr[j] += __shfl_xor(ssr[j], off, 64);
    if (lane == 0) {
        #pragma unroll
        for (int j = 0; j < 8; j++) ssq[kw * 8 + j] = ssr[j];
    }
    __syncthreads();
    if (t < 64) {
        float nrm = sqrtf(ssq[t]);
        float inv = 1.f / fmaxf(nrm, 1e-12f);
        float sk = nrm * inv;
        float g = sk * sk;
        #pragma unroll
        for (int off = 32; off >= 1; off >>= 1) g += __shfl_xor(g, off, 64);
        scl[t] = inv * (1.f / fmaxf(sqrtf(g), 1e-12f));
    }
    __syncthreads();
    #pragma unroll
    for (int j = 0; j < 8; j++) {
        int k = kw * 8 + j;
        float s2 = scl[k];
        float4 o1 = make_float4(accA[j][0] * s2, accA[j][1] * s2, accA[j][2] * s2, accA[j][3] * s2);
        float4 o2 = make_float4(accB[j][0] * s2, accB[j][1] * s2, accB[j][2] * s2, accB[j][3] * s2);
        *(float4*)&out[(size_t)n * 32768 + (size_t)k * 512 + c0] = o1;
        *(float4*)&out[(size_t)n * 32768 + (size_t)k * 512 + 256 + c0] = o2;
    }
}

extern "C" void kernel_launch(void* const* d_in, const int* in_sizes, int n_in,
                              void* d_out, int out_size, void* d_ws, size_t ws_size,
                              hipStream_t stream)
{
    const float* x     = (const float*)d_in[0];
    const float* cent  = (const float*)d_in[1];
    const float* convw = (const float*)d_in[2];
    const float* convb = (const float*)d_in[3];
    const float* lnw   = (const float*)d_in[4];
    const float* lnb   = (const float*)d_in[5];
    const float* c3w   = (const float*)d_in[6];
    const float* c3b   = (const float*)d_in[7];
    const float* c5w   = (const float*)d_in[8];
    const float* c5b   = (const float*)d_in[9];
    const float* c7w   = (const float*)d_in[10];
    const float* c7b   = (const float*)d_in[11];
    const float* dww   = (const float*)d_in[12];
    const float* dwb   = (const float*)d_in[13];
    const float* dhw   = (const float*)d_in[14];
    const float* dhb   = (const float*)d_in[15];
    const float* accw  = (const float*)d_in[16];
    const float* accb  = (const float*)d_in[17];
    float* out = (float*)d_out;

    char* ws = (char*)d_ws;
    float* Gmat = (float*)(ws);                 // 512*2401*4 = 4,917,248
    float* Gl   = (float*)(ws + 4917248);       // 512*49*4  = 100,352
    float* Cb   = (float*)(ws + 5017600);       // 256
    float* part = (float*)(ws + 5017856);       // 256*25088*4 = 25,690,112 (end ~30.7MB)

    kG   <<<512, 256, 0, stream>>>(c3w, c5w, c7w, dww, dhw, accw, lnw, lnb, Gmat, Gl);
    kCb  <<<1,   64,  0, stream>>>(c3b, c5b, c7b, dww, dwb, dhw, dhb, accw, accb, Gl, Cb);
    kCw1 <<<512, 256, 0, stream>>>(x, Gmat, part);
    kMain<<<512, 512, 0, stream>>>(x, convw, convb, part, Cb, cent, out);
}